// Round 2
// baseline (729.635 us; speedup 1.0000x reference)
//
#include <hip/hip_runtime.h>
#include <hip/hip_bf16.h>
#include <math.h>

// Only rows (b, n==0) can reach the output slice [:,0,-1,:] -> 4 sequences x 64 pos.
// Single fused kernel, 32 wgs x 256 thr, hand-rolled grid barrier (generation slots;
// 0xAA poison = negative int so no init needed), agent fences for XCD L2 non-coherence.

#define NWG 32

// Workspace layout (float offsets)
#define WS_RESIDUAL 0          // 256*128
#define WS_XZ       32768      // 256*512
#define WS_Y        303104     // 256*256
#define WS_BAR      368640     // NWG int slots

__device__ __forceinline__ float silu_f(float v) {
    return v / (1.0f + __expf(-v));
}

// grid barrier: each wg publishes generation g to its slot, spins until all slots >= g.
// Poisoned slots are 0xAAAAAAAA (negative as int) -> block until written this launch.
__device__ __forceinline__ void gbar(int* slots, int gen) {
    __syncthreads();
    if (threadIdx.x == 0) {
        __threadfence();   // agent release: writeback this XCD's L2 (data -> LLC)
        __hip_atomic_store(&slots[blockIdx.x], gen, __ATOMIC_RELEASE, __HIP_MEMORY_SCOPE_AGENT);
    }
    if (threadIdx.x < NWG) {
        while (__hip_atomic_load(&slots[threadIdx.x], __ATOMIC_ACQUIRE,
                                 __HIP_MEMORY_SCOPE_AGENT) < gen) {}
    }
    if (threadIdx.x == 0) __threadfence();  // agent acquire: invalidate stale L1/L2
    __syncthreads();
}

union __align__(16) SMem {
    struct {
        float gated[8][256];
        float res[8][128];
        float hn[8][128];
        float part[8][32];
        float scale[8];
    } kin;
    struct {
        union { float uChunk[16][256]; float dtm[64][64]; } a; // dtm reuses uChunk after conv
        float uOwn[64][64];
        float xdbl[64][48];   // 40 used, stride 48
    } scan;
    struct {
        float gated[256];
        float partial[2][128];
        float resf[128];
        float part[32];
        float scale;
        int valid;
    } fin;
};

__global__ __launch_bounds__(256) void fused_kernel(
    const float* __restrict__ mha_in, const int* __restrict__ mask,
    const float* __restrict__ mlp_w1, const float* __restrict__ mlp_b1,
    const float* __restrict__ mlp_w2, const float* __restrict__ mlp_b2,
    const float* __restrict__ in_proj_w,
    const float* __restrict__ conv_w, const float* __restrict__ conv_b,
    const float* __restrict__ x_proj_w,
    const float* __restrict__ dt_proj_w, const float* __restrict__ dt_proj_b,
    const float* __restrict__ A_log, const float* __restrict__ D_skip,
    const float* __restrict__ out_proj_w,
    const float* __restrict__ blk_norm_w, const float* __restrict__ norm_f_w,
    float* __restrict__ ws, float* __restrict__ out)
{
    __shared__ SMem sm;

    float* residual = ws + WS_RESIDUAL;
    float* xz       = ws + WS_XZ;
    float* ybuf     = ws + WS_Y;
    int*   slots    = (int*)(ws + WS_BAR);

    const int tid = threadIdx.x;
    const int bid = blockIdx.x;

    for (int layer = 0; layer < 4; ++layer) {
        // ============ phase A: [mlp|gate+out_proj]+residual+rmsnorm+in_proj ======
        {
            const int row0 = bid * 8;
            if (layer == 0) {
                for (int idx = tid; idx < 8*128; idx += 256) {
                    int i = idx >> 7, c = idx & 127;
                    int r = row0 + i; int s = r >> 6, l = r & 63;
                    sm.kin.gated[i][c] = mha_in[(s*4096 + l)*128 + c];
                }
                __syncthreads();
                {   // h1 = gelu(x @ w1^T + b1) -> gated[i][128+j]
                    int jg = tid & 63, rq = tid >> 6;
                    int j0 = jg*2;
                    float acc[2][2] = {{0.f,0.f},{0.f,0.f}};
                    for (int k4 = 0; k4 < 32; ++k4) {
                        float4 w0 = *(const float4*)&mlp_w1[(j0  )*128 + k4*4];
                        float4 w1 = *(const float4*)&mlp_w1[(j0+1)*128 + k4*4];
                        #pragma unroll
                        for (int rr = 0; rr < 2; ++rr) {
                            float4 xv = *(const float4*)&sm.kin.gated[rq*2+rr][k4*4];
                            acc[rr][0] += xv.x*w0.x + xv.y*w0.y + xv.z*w0.z + xv.w*w0.w;
                            acc[rr][1] += xv.x*w1.x + xv.y*w1.y + xv.z*w1.z + xv.w*w1.w;
                        }
                    }
                    __syncthreads();
                    #pragma unroll
                    for (int rr = 0; rr < 2; ++rr)
                        #pragma unroll
                        for (int jj = 0; jj < 2; ++jj) {
                            float v = acc[rr][jj] + mlp_b1[j0+jj];
                            sm.kin.gated[rq*2+rr][128 + j0 + jj] =
                                0.5f*v*(1.0f + erff(v*0.70710678118f));
                        }
                }
                __syncthreads();
                {   // h2 = h1 @ w2^T + b2
                    int jg = tid & 63, rq = tid >> 6;
                    int j0 = jg*2;
                    float acc[2][2] = {{0.f,0.f},{0.f,0.f}};
                    for (int k4 = 0; k4 < 32; ++k4) {
                        float4 w0 = *(const float4*)&mlp_w2[(j0  )*128 + k4*4];
                        float4 w1 = *(const float4*)&mlp_w2[(j0+1)*128 + k4*4];
                        #pragma unroll
                        for (int rr = 0; rr < 2; ++rr) {
                            float4 xv = *(const float4*)&sm.kin.gated[rq*2+rr][128 + k4*4];
                            acc[rr][0] += xv.x*w0.x + xv.y*w0.y + xv.z*w0.z + xv.w*w0.w;
                            acc[rr][1] += xv.x*w1.x + xv.y*w1.y + xv.z*w1.z + xv.w*w1.w;
                        }
                    }
                    #pragma unroll
                    for (int rr = 0; rr < 2; ++rr) {
                        int i = rq*2 + rr, r = row0 + i;
                        #pragma unroll
                        for (int jj = 0; jj < 2; ++jj) {
                            float v = acc[rr][jj] + mlp_b2[j0+jj];
                            sm.kin.res[i][j0+jj] = v;
                            residual[r*128 + j0 + jj] = v;
                        }
                    }
                }
            } else {
                for (int idx = tid; idx < 8*256; idx += 256) {
                    int i = idx >> 8, dd = idx & 255;
                    int r = row0 + i;
                    float yv = ybuf[r*256 + dd];
                    float zv = xz[r*512 + 256 + dd];
                    sm.kin.gated[i][dd] = yv * silu_f(zv);
                }
                __syncthreads();
                {
                    const float* ow = out_proj_w + (size_t)(layer-1)*128*256;
                    int jg = tid & 63, rq = tid >> 6;
                    int j0 = jg*2;
                    float acc[2][2] = {{0.f,0.f},{0.f,0.f}};
                    for (int k4 = 0; k4 < 64; ++k4) {
                        float4 w0 = *(const float4*)&ow[(j0  )*256 + k4*4];
                        float4 w1 = *(const float4*)&ow[(j0+1)*256 + k4*4];
                        #pragma unroll
                        for (int rr = 0; rr < 2; ++rr) {
                            float4 xv = *(const float4*)&sm.kin.gated[rq*2+rr][k4*4];
                            acc[rr][0] += xv.x*w0.x + xv.y*w0.y + xv.z*w0.z + xv.w*w0.w;
                            acc[rr][1] += xv.x*w1.x + xv.y*w1.y + xv.z*w1.z + xv.w*w1.w;
                        }
                    }
                    #pragma unroll
                    for (int rr = 0; rr < 2; ++rr) {
                        int i = rq*2 + rr, r = row0 + i;
                        #pragma unroll
                        for (int jj = 0; jj < 2; ++jj) {
                            float v = acc[rr][jj] + residual[r*128 + j0 + jj];
                            sm.kin.res[i][j0+jj] = v;
                            residual[r*128 + j0 + jj] = v;
                        }
                    }
                }
            }
            __syncthreads();
            // rmsnorm
            {
                int r = tid >> 5, lane = tid & 31;
                float sq = 0.f;
                #pragma unroll
                for (int t = 0; t < 4; ++t) { float v = sm.kin.res[r][lane + 32*t]; sq += v*v; }
                sm.kin.part[r][lane] = sq;
            }
            __syncthreads();
            if (tid < 8) {
                float sq = 0.f;
                #pragma unroll
                for (int t = 0; t < 32; ++t) sq += sm.kin.part[tid][t];
                sm.kin.scale[tid] = rsqrtf(sq * (1.0f/128.0f) + 1e-5f);
            }
            __syncthreads();
            {
                const float* bw = blk_norm_w + layer*128;
                for (int idx = tid; idx < 8*128; idx += 256) {
                    int i = idx >> 7, c = idx & 127;
                    sm.kin.hn[i][c] = sm.kin.res[i][c] * sm.kin.scale[i] * bw[c];
                }
            }
            __syncthreads();
            // xz = hn @ in_w^T (8 x 512, K=128)
            {
                const float* iw = in_proj_w + (size_t)layer*512*128;
                int jg = tid & 127, rh = tid >> 7;
                int j0 = jg*4;
                float acc[4][4] = {};
                for (int k4 = 0; k4 < 32; ++k4) {
                    float4 w[4];
                    #pragma unroll
                    for (int jj = 0; jj < 4; ++jj)
                        w[jj] = *(const float4*)&iw[(j0+jj)*128 + k4*4];
                    #pragma unroll
                    for (int rr = 0; rr < 4; ++rr) {
                        float4 xv = *(const float4*)&sm.kin.hn[rh*4+rr][k4*4];
                        #pragma unroll
                        for (int jj = 0; jj < 4; ++jj)
                            acc[rr][jj] += xv.x*w[jj].x + xv.y*w[jj].y + xv.z*w[jj].z + xv.w*w[jj].w;
                    }
                }
                #pragma unroll
                for (int rr = 0; rr < 4; ++rr) {
                    int r = row0 + rh*4 + rr;
                    float4 o; o.x = acc[rr][0]; o.y = acc[rr][1]; o.z = acc[rr][2]; o.w = acc[rr][3];
                    *(float4*)&xz[r*512 + j0] = o;
                }
            }
        }
        gbar(slots, layer*2 + 1);

        // ============ phase B: conv+silu + x_proj + dt + serial scan (16 wgs) =====
        if (bid < 16) {
            const int s  = bid >> 2;
            const int db = bid & 3;
            // conv over all 64 rows, 4 chunks of 16; xm carried in regs across chunks
            {
                const int d = tid;
                const float* cw = conv_w + (size_t)(layer*256 + d)*4;
                float w0 = cw[0], w1 = cw[1], w2 = cw[2], w3 = cw[3];
                float cb = conv_b[layer*256 + d];
                float xm3 = 0.f, xm2 = 0.f, xm1 = 0.f;
                for (int c = 0; c < 4; ++c) {
                    const int r0 = s*64 + c*16;
                    for (int l = 0; l < 16; ++l) {
                        float x0 = xz[(size_t)(r0 + l)*512 + d];
                        float v  = cb + w0*xm3 + w1*xm2 + w2*xm1 + w3*x0;
                        sm.scan.a.uChunk[l][d] = silu_f(v);
                        xm3 = xm2; xm2 = xm1; xm1 = x0;
                    }
                    __syncthreads();
                    // x_proj for these 16 rows (16 x 40, K=256)
                    {
                        int l = tid >> 4, jg = tid & 15;
                        if (jg < 10) {
                            int j0 = jg*4;
                            const float* xw = x_proj_w + (size_t)layer*40*256;
                            float acc[4] = {0.f,0.f,0.f,0.f};
                            for (int k4 = 0; k4 < 64; ++k4) {
                                float4 uv = *(const float4*)&sm.scan.a.uChunk[l][k4*4];
                                #pragma unroll
                                for (int jj = 0; jj < 4; ++jj) {
                                    float4 w = *(const float4*)&xw[(j0+jj)*256 + k4*4];
                                    acc[jj] += uv.x*w.x + uv.y*w.y + uv.z*w.z + uv.w*w.w;
                                }
                            }
                            #pragma unroll
                            for (int jj = 0; jj < 4; ++jj)
                                sm.scan.xdbl[c*16 + l][j0+jj] = acc[jj];
                        }
                    }
                    // keep own 64 channels
                    #pragma unroll
                    for (int p = 0; p < 4; ++p) {
                        int e = tid + 256*p;          // < 1024
                        int l = e >> 6, ch = e & 63;
                        sm.scan.uOwn[c*16 + l][ch] = sm.scan.a.uChunk[l][db*64 + ch];
                    }
                    __syncthreads();
                }
            }
            // dt = softplus(xdbl[:,:8] @ dtw^T + dtb) -> dtm (aliases uChunk, done with it)
            {
                int ch = tid & 63, lg = tid >> 6;
                const float* dw = dt_proj_w + (size_t)(layer*256 + db*64 + ch)*8;
                float w[8];
                #pragma unroll
                for (int t = 0; t < 8; ++t) w[t] = dw[t];
                float bdt = dt_proj_b[layer*256 + db*64 + ch];
                for (int l = lg*16; l < lg*16 + 16; ++l) {
                    float pre = bdt;
                    #pragma unroll
                    for (int t = 0; t < 8; ++t) pre += sm.scan.xdbl[l][t]*w[t];
                    sm.scan.a.dtm[l][ch] = (pre > 20.f) ? pre : log1pf(__expf(pre));
                }
            }
            __syncthreads();
            // serial scan, all operands in LDS, 1-step prefetch
            {
                const int dloc = tid >> 2, sub = tid & 3;
                const int d = db*64 + dloc;
                float A[4], h[4] = {0.f,0.f,0.f,0.f};
                #pragma unroll
                for (int j = 0; j < 4; ++j)
                    A[j] = -__expf(A_log[(size_t)(layer*256 + d)*16 + sub*4 + j]);
                float Dsk = D_skip[layer*256 + d];

                float dtv = sm.scan.a.dtm[0][dloc];
                float uv  = sm.scan.uOwn[0][dloc];
                float4 B4 = *(const float4*)&sm.scan.xdbl[0][ 8 + sub*4];
                float4 C4 = *(const float4*)&sm.scan.xdbl[0][24 + sub*4];

                for (int l = 0; l < 64; ++l) {
                    float dtn = 0.f, un = 0.f; float4 Bn = {0,0,0,0}, Cn = {0,0,0,0};
                    if (l < 63) {
                        dtn = sm.scan.a.dtm[l+1][dloc];
                        un  = sm.scan.uOwn[l+1][dloc];
                        Bn  = *(const float4*)&sm.scan.xdbl[l+1][ 8 + sub*4];
                        Cn  = *(const float4*)&sm.scan.xdbl[l+1][24 + sub*4];
                    }
                    float du = dtv * uv;
                    float yp = 0.f, dA;
                    dA = __expf(dtv*A[0]); h[0] = dA*h[0] + du*B4.x; yp += h[0]*C4.x;
                    dA = __expf(dtv*A[1]); h[1] = dA*h[1] + du*B4.y; yp += h[1]*C4.y;
                    dA = __expf(dtv*A[2]); h[2] = dA*h[2] + du*B4.z; yp += h[2]*C4.z;
                    dA = __expf(dtv*A[3]); h[3] = dA*h[3] + du*B4.w; yp += h[3]*C4.w;
                    yp += __shfl_xor(yp, 1);
                    yp += __shfl_xor(yp, 2);
                    if (sub == 0) ybuf[(size_t)(s*64 + l)*256 + d] = yp + uv*Dsk;
                    dtv = dtn; uv = un; B4 = Bn; C4 = Cn;
                }
            }
        }
        gbar(slots, layer*2 + 2);
    }

    // ============ final: gate + out_proj(row l=63) + residual + rmsnorm + mask ====
    if (bid < 4) {
        const int s2 = bid;
        const int row = s2*64 + 63;
        if (tid == 0) sm.fin.valid = 0;
        __syncthreads();
        if (tid < 64 && mask[s2*4096 + tid] != 0) sm.fin.valid = 1;  // benign race
        sm.fin.gated[tid] = ybuf[(size_t)row*256 + tid] * silu_f(xz[(size_t)row*512 + 256 + tid]);
        __syncthreads();
        {
            const float* ow = out_proj_w + (size_t)3*128*256;
            int jj = tid & 127, half = tid >> 7;
            float acc = 0.f;
            for (int k4 = half*32; k4 < half*32 + 32; ++k4) {
                float4 w = *(const float4*)&ow[jj*256 + k4*4];
                float4 g = *(const float4*)&sm.fin.gated[k4*4];
                acc += g.x*w.x + g.y*w.y + g.z*w.z + g.w*w.w;
            }
            sm.fin.partial[half][jj] = acc;
        }
        __syncthreads();
        if (tid < 128) {
            float v = sm.fin.partial[0][tid] + sm.fin.partial[1][tid]
                    + residual[(size_t)row*128 + tid];
            sm.fin.resf[tid] = v;
        }
        __syncthreads();
        if (tid < 32) {
            float sq = 0.f;
            #pragma unroll
            for (int t = 0; t < 4; ++t) { float v = sm.fin.resf[tid + 32*t]; sq += v*v; }
            sm.fin.part[tid] = sq;
        }
        __syncthreads();
        if (tid == 0) {
            float sq = 0.f;
            #pragma unroll
            for (int t = 0; t < 32; ++t) sq += sm.fin.part[t];
            sm.fin.scale = rsqrtf(sq * (1.0f/128.0f) + 1e-5f);
        }
        __syncthreads();
        if (tid < 128) {
            float v = sm.fin.resf[tid] * sm.fin.scale * norm_f_w[tid];
            out[s2*128 + tid] = sm.fin.valid ? v : 0.f;
        }
    }
}

// ---------------------------------------------------------------------------
extern "C" void kernel_launch(void* const* d_in, const int* in_sizes, int n_in,
                              void* d_out, int out_size, void* d_ws, size_t ws_size,
                              hipStream_t stream) {
    const float* mha_in     = (const float*)d_in[0];
    const int*   mask       = (const int*)  d_in[1];
    const float* mlp_w1     = (const float*)d_in[2];
    const float* mlp_b1     = (const float*)d_in[3];
    const float* mlp_w2     = (const float*)d_in[4];
    const float* mlp_b2     = (const float*)d_in[5];
    const float* in_proj_w  = (const float*)d_in[6];
    const float* conv_w     = (const float*)d_in[7];
    const float* conv_b     = (const float*)d_in[8];
    const float* x_proj_w   = (const float*)d_in[9];
    const float* dt_proj_w  = (const float*)d_in[10];
    const float* dt_proj_b  = (const float*)d_in[11];
    const float* A_log      = (const float*)d_in[12];
    const float* D_skip     = (const float*)d_in[13];
    const float* out_proj_w = (const float*)d_in[14];
    const float* blk_norm_w = (const float*)d_in[15];
    const float* norm_f_w   = (const float*)d_in[16];
    float* ws  = (float*)d_ws;
    float* out = (float*)d_out;

    fused_kernel<<<NWG, 256, 0, stream>>>(mha_in, mask, mlp_w1, mlp_b1, mlp_w2, mlp_b2,
                                          in_proj_w, conv_w, conv_b, x_proj_w,
                                          dt_proj_w, dt_proj_b, A_log, D_skip,
                                          out_proj_w, blk_norm_w, norm_f_w, ws, out);
}